// Round 5
// baseline (232.558 us; speedup 1.0000x reference)
//
#include <hip/hip_runtime.h>
#include <math.h>

// Problem shape (fixed by the reference): x = (B=4, S=8192, D=1024) float32.
// out[b,s,d] = x[b,s,d] + pos[s,d]
//   pos[s,d] = sin(s / 10000^((d+1)/D)) if d even, cos(...) if d odd.
#define PE_S 8192
#define PE_D 1024
#define PE_B 4

#define PE_BLOCKS 2048
#define PE_THREADS 256
#define PE_QTOTAL (PE_B * PE_S * PE_D / 4)   // 8,388,608 float4 quads
#define PE_NT (PE_BLOCKS * PE_THREADS)       // 524,288 threads
#define PE_ITERS (PE_QTOTAL / PE_NT)         // 16 quads per thread

typedef float f32x4 __attribute__((ext_vector_type(4)));

// Native-trig positional value (branch-free, single BB). v_sin/cos take
// REVOLUTIONS; wrev = 10000^-((j+1)/D) / (2pi) folds -log2(2pi) into one
// v_exp_f32. fmaf residual keeps the fract reduction effectively fp64;
// absmax has stayed 0.03125 across all rounds with this path.
__device__ __forceinline__ float pe_sin(float fs, float wrev) {
    float t = fs * wrev;
    float r = t - floorf(t);
    r += fmaf(fs, wrev, -t);            // exact product residual
    return __builtin_amdgcn_sinf(r);    // sin(2*pi*r)
}
__device__ __forceinline__ float pe_cos(float fs, float wrev) {
    float t = fs * wrev;
    float r = t - floorf(t);
    r += fmaf(fs, wrev, -t);
    return __builtin_amdgcn_cosf(r);    // cos(2*pi*r)
}

// m13-STYLE RESIDENT COPY STRUCTURE, explicitly software-pipelined.
// History: one-shot linear = 72us (3.7 TB/s combined); naive resident loop
// (r3) REGRESSED to 85us because the compiler did not pipeline (VGPR=32):
// loads and stores share the in-order vmcnt counter, so each iteration's
// load-wait sat behind the previous iteration's store. Fix: manual depth-2
// prefetch with NAMED rotation registers (no runtime-indexed arrays ->
// no scratch, rule #20). Steady state per wave: ~2 loads + ~2 stores in
// flight, counted vmcnt waits, never a full drain. Pure linear streams
// (no plane pairing -- r4 showed extra per-wave MLP buys nothing), plain
// loads/stores (nt proven neutral r1/r4). 2048 blocks x 256 = 32 waves/CU.
// Stride PE_NT is a multiple of 256 quads -> d0 constant per thread ->
// the 4 exp2f weights are computed once; only s changes per iteration.
__global__ __launch_bounds__(PE_THREADS) void position_encoder_kernel(
    const float* __restrict__ x, float* __restrict__ out) {
    const int tid0 = blockIdx.x * blockDim.x + threadIdx.x;  // 0..524287
    const int d0   = (tid0 & (PE_D / 4 - 1)) << 2;           // constant

    const float A2 = -0.012976281620653760f;  // -log2(10000)/1024
    const float C  = -2.6514961294723187f;    // -log2(2*pi)
    const float w0 = exp2f(fmaf((float)(d0 + 1), A2, C));
    const float w1 = exp2f(fmaf((float)(d0 + 2), A2, C));
    const float w2 = exp2f(fmaf((float)(d0 + 3), A2, C));
    const float w3 = exp2f(fmaf((float)(d0 + 4), A2, C));

    // ---- prologue: 2 loads in flight before any compute/store ----
    f32x4 cur0 = *reinterpret_cast<const f32x4*>(x + (size_t)(tid0 + 0 * PE_NT) * 4);
    f32x4 cur1 = *reinterpret_cast<const f32x4*>(x + (size_t)(tid0 + 1 * PE_NT) * 4);

#pragma unroll
    for (int it = 0; it < PE_ITERS; ++it) {
        // issue prefetch for it+2 FIRST (independent of everything below)
        f32x4 nxt = {0.f, 0.f, 0.f, 0.f};
        if (it + 2 < PE_ITERS) {
            nxt = *reinterpret_cast<const f32x4*>(
                x + (size_t)(tid0 + (it + 2) * PE_NT) * 4);
        }

        const int q = tid0 + it * PE_NT;
        const int s = (q >> 8) & (PE_S - 1);
        const float fs = (float)s;

        f32x4 p;
        p.x = pe_sin(fs, w0);   // d0   even -> sin
        p.y = pe_cos(fs, w1);   // d0+1 odd  -> cos
        p.z = pe_sin(fs, w2);   // d0+2 even -> sin
        p.w = pe_cos(fs, w3);   // d0+3 odd  -> cos

        *reinterpret_cast<f32x4*>(out + (size_t)q * 4) = cur0 + p;

        // rotate (named registers -> stays in VGPRs under full unroll)
        cur0 = cur1;
        cur1 = nxt;
    }
}

extern "C" void kernel_launch(void* const* d_in, const int* in_sizes, int n_in,
                              void* d_out, int out_size, void* d_ws, size_t ws_size,
                              hipStream_t stream) {
    const float* x = (const float*)d_in[0];
    float* out = (float*)d_out;
    position_encoder_kernel<<<PE_BLOCKS, PE_THREADS, 0, stream>>>(x, out);
}